// Round 5
// baseline (470.151 us; speedup 1.0000x reference)
//
#include <hip/hip_runtime.h>

// ---------------------------------------------------------------------------
// SemanticMemoryLatentSpace, fully factored:
//   K_final = g*K0 + sum_s w_s e_s e_s^T   (scalar recurrence for g, w)
//   centroids C_j = d_j * sum_{s in j} bhat_s e_s  -> sims via Gram matrix
// Single-wave scan, TWO steps per iteration (one LDS round-trip per pair):
//   RAW[j][c] = sum_{s in j} bhat_s G[s,c] for current 128-col block;
//   step t+1's column is patched in-register (only row idx_t changed).
//   Q[c] = sum_s what_s G[s,c]^2 in registers; n2/g lag chain off the
//   decision path. Cross-lane via DPP + readlane only.
// ---------------------------------------------------------------------------

#define A_BOOSTF 0.012247448713915891f // 1.5*alpha (growth==0 always => boosted)

template <int CTRL>
__device__ __forceinline__ float dpp_f(float x) {
  return __int_as_float(
      __builtin_amdgcn_mov_dpp(__float_as_int(x), CTRL, 0xf, 0xf, true));
}
__device__ __forceinline__ float rdlane_f(float x, int l) {
  return __int_as_float(__builtin_amdgcn_readlane(__float_as_int(x), l));
}
__device__ __forceinline__ float wave_sum64(float v) {
  v += dpp_f<0xB1>(v);    // quad_perm [1,0,3,2]
  v += dpp_f<0x4E>(v);    // quad_perm [2,3,0,1]
  v += dpp_f<0x124>(v);   // row_ror:4
  v += dpp_f<0x128>(v);   // row_ror:8
  return (rdlane_f(v, 0) + rdlane_f(v, 16)) + (rdlane_f(v, 32) + rdlane_f(v, 48));
}
__device__ __forceinline__ float wave_max64(float v) {
  v = fmaxf(v, dpp_f<0xB1>(v));
  v = fmaxf(v, dpp_f<0x4E>(v));
  v = fmaxf(v, dpp_f<0x124>(v));
  v = fmaxf(v, dpp_f<0x128>(v));
  return fmaxf(fmaxf(rdlane_f(v, 0), rdlane_f(v, 16)),
               fmaxf(rdlane_f(v, 32), rdlane_f(v, 48)));
}

// ---------------- generic 32x32-tile fp32 GEMMs -----------------------------
__global__ __launch_bounds__(256) void gemm_nt(const float* __restrict__ A,
                                               const float* __restrict__ B,
                                               float* __restrict__ C,
                                               int N, int K) {
  __shared__ float As[32][33];
  __shared__ float Bs[32][33];
  int bx = blockIdx.x, by = blockIdx.y;
  int tid = threadIdx.x;
  int tx = tid & 15, ty = tid >> 4;
  float a00 = 0.f, a01 = 0.f, a10 = 0.f, a11 = 0.f;
  for (int k0 = 0; k0 < K; k0 += 32) {
    for (int l = tid; l < 1024; l += 256) {
      int r = l >> 5, c = l & 31;
      As[r][c] = A[(by * 32 + r) * K + k0 + c];
      Bs[r][c] = B[(bx * 32 + r) * K + k0 + c];
    }
    __syncthreads();
#pragma unroll
    for (int k = 0; k < 32; ++k) {
      float x0 = As[2 * ty][k], x1 = As[2 * ty + 1][k];
      float y0 = Bs[2 * tx][k], y1 = Bs[2 * tx + 1][k];
      a00 += x0 * y0; a01 += x0 * y1; a10 += x1 * y0; a11 += x1 * y1;
    }
    __syncthreads();
  }
  int i = by * 32 + 2 * ty, jj = bx * 32 + 2 * tx;
  C[i * N + jj] = a00;           C[i * N + jj + 1] = a01;
  C[(i + 1) * N + jj] = a10;     C[(i + 1) * N + jj + 1] = a11;
}

__global__ __launch_bounds__(256) void gemm_nn(const float* __restrict__ A,
                                               const float* __restrict__ B,
                                               float* __restrict__ C,
                                               int N, int K) {
  __shared__ float As[32][33];
  __shared__ float Bs[32][33];
  int bx = blockIdx.x, by = blockIdx.y;
  int tid = threadIdx.x;
  int tx = tid & 15, ty = tid >> 4;
  float a00 = 0.f, a01 = 0.f, a10 = 0.f, a11 = 0.f;
  for (int k0 = 0; k0 < K; k0 += 32) {
    for (int l = tid; l < 1024; l += 256) {
      int r = l >> 5, c = l & 31;
      As[r][c] = A[(by * 32 + r) * K + k0 + c];
      Bs[r][c] = B[(k0 + r) * N + bx * 32 + c];
    }
    __syncthreads();
#pragma unroll
    for (int k = 0; k < 32; ++k) {
      float x0 = As[2 * ty][k], x1 = As[2 * ty + 1][k];
      float y0 = Bs[k][2 * tx], y1 = Bs[k][2 * tx + 1];
      a00 += x0 * y0; a01 += x0 * y1; a10 += x1 * y0; a11 += x1 * y1;
    }
    __syncthreads();
  }
  int i = by * 32 + 2 * ty, jj = bx * 32 + 2 * tx;
  C[i * N + jj] = a00;           C[i * N + jj + 1] = a01;
  C[(i + 1) * N + jj] = a10;     C[(i + 1) * N + jj + 1] = a11;
}

// out[i][j] = g*M0[i][j] + sum_s G[i][s]*W[s]*E[s][j]
__global__ __launch_bounds__(256) void final_gemm(const float* __restrict__ G,
                                                  const float* __restrict__ E,
                                                  const float* __restrict__ M0,
                                                  const float* __restrict__ W,
                                                  const float* __restrict__ gS,
                                                  float* __restrict__ out) {
  __shared__ float As[32][33];
  __shared__ float Bs[32][33];
  int bx = blockIdx.x, by = blockIdx.y;
  int tid = threadIdx.x;
  int tx = tid & 15, ty = tid >> 4;
  float a00 = 0.f, a01 = 0.f, a10 = 0.f, a11 = 0.f;
  for (int k0 = 0; k0 < 512; k0 += 32) {
    for (int l = tid; l < 1024; l += 256) {
      int r = l >> 5, c = l & 31;
      As[r][c] = G[(by * 32 + r) * 512 + k0 + c] * W[k0 + c];
      Bs[r][c] = E[(k0 + r) * 384 + bx * 32 + c];
    }
    __syncthreads();
#pragma unroll
    for (int k = 0; k < 32; ++k) {
      float x0 = As[2 * ty][k], x1 = As[2 * ty + 1][k];
      float y0 = Bs[k][2 * tx], y1 = Bs[k][2 * tx + 1];
      a00 += x0 * y0; a01 += x0 * y1; a10 += x1 * y0; a11 += x1 * y1;
    }
    __syncthreads();
  }
  float gv = gS[0];
  int i = by * 32 + 2 * ty, jj = bx * 32 + 2 * tx;
  out[i * 384 + jj]         = gv * M0[i * 384 + jj]         + a00;
  out[i * 384 + jj + 1]     = gv * M0[i * 384 + jj + 1]     + a01;
  out[(i + 1) * 384 + jj]     = gv * M0[(i + 1) * 384 + jj]     + a10;
  out[(i + 1) * 384 + jj + 1] = gv * M0[(i + 1) * 384 + jj + 1] + a11;
}

// prep: blocks 0..127 -> u[row] = dot(M0[row], E[row]) (one wave per row)
//       blocks 128..191 -> Kpart[cb] = partial ||K0||_F^2 (deterministic)
__global__ __launch_bounds__(256) void prep_kernel(const float* __restrict__ E,
                                                   const float* __restrict__ M0,
                                                   const float* __restrict__ K0,
                                                   float* __restrict__ u,
                                                   float* __restrict__ Kpart) {
  __shared__ double wr[4];
  int b = blockIdx.x;
  int tid = threadIdx.x, lane = tid & 63, wv = tid >> 6;
  if (b < 128) {
    int row = b * 4 + wv;
    const float4* e4 = (const float4*)(E + row * 384);
    const float4* m4 = (const float4*)(M0 + row * 384);
    float p = 0.f;
    for (int i = lane; i < 96; i += 64) {
      float4 a = e4[i], bb = m4[i];
      p += a.x * bb.x + a.y * bb.y + a.z * bb.z + a.w * bb.w;
    }
#pragma unroll
    for (int off = 32; off; off >>= 1) p += __shfl_down(p, off);
    if (lane == 0) u[row] = p;
  } else {
    int cb = b - 128;                            // 0..63
    const float* p = K0 + cb * 2304 + tid * 9;   // 64*256*9 = 147456 exactly
    double acc = 0.0;
#pragma unroll
    for (int i = 0; i < 9; ++i) { double v = (double)p[i]; acc += v * v; }
#pragma unroll
    for (int off = 32; off; off >>= 1) acc += __shfl_down(acc, off);
    if (lane == 0) wr[wv] = acc;
    __syncthreads();
    if (tid == 0) Kpart[cb] = (float)(wr[0] + wr[1] + wr[2] + wr[3]);
  }
}

// ---------------- single-wave scan, 2 steps/iteration ----------------------
__global__ __launch_bounds__(64) void scan_kernel(const float* __restrict__ G,
                                                  const float* __restrict__ u,
                                                  const float* __restrict__ Kpart,
                                                  float* __restrict__ Wout,
                                                  float* __restrict__ gOut) {
  __shared__ float RAW[128 * 129];   // [cluster][col], pad -> 2-way banks
  __shared__ float4 SLOT[512];       // journal: {bhat, what, idx, 0}
  __shared__ float u_sh[512];

  const int lane = threadIdx.x;
  const int ro0 = lane * 129, ro1 = (lane + 64) * 129;

  ((float4*)u_sh)[lane] = ((const float4*)u)[lane];
  ((float4*)u_sh)[lane + 64] = ((const float4*)u)[lane + 64];

  // per-cluster state: clusters (lane) and (lane+64); s = d / sqrt(cn2)
  float d0 = 1.f, d1 = 1.f, cn0 = 0.f, cn1 = 0.f, s0 = 0.f, s1 = 0.f;
  float n2 = wave_sum64(Kpart[lane]);
  float g = 1.f, ginv = 1.f, q0 = 0.f, q1 = 0.f;
  int nact = 0;

  float4 z4 = {0.f, 0.f, 0.f, 0.f};
  for (int i = lane; i < 4128; i += 64) ((float4*)RAW)[i] = z4;

  float ga0 = G[lane], ga1 = G[64 + lane];           // row t block cols
  float gb0 = G[512 + lane], gb1 = G[512 + 64 + lane]; // row t+1
  float r0a = 0.f, r1a = 0.f, r0b = 0.f, r1b = 0.f;  // cols c, c+1

  for (int t = 0; t < 512; t += 2) {
    const int c = t & 127, c1 = c + 1;
    if (t && c == 0) {
      // ---- block-boundary rebuild for cols [t, t+128) ----
      for (int i = lane; i < 4128; i += 64) ((float4*)RAW)[i] = z4;
      q0 = 0.f; q1 = 0.f;
      __builtin_amdgcn_sched_barrier(0);
      const float* Gb = G + t;
      for (int s = 0; s < t; s += 8) {
        float a0[8], a1[8];
        float4 sl[8];
#pragma unroll
        for (int j = 0; j < 8; ++j) {
          a0[j] = Gb[(s + j) * 512 + lane];
          a1[j] = Gb[(s + j) * 512 + 64 + lane];
          sl[j] = SLOT[s + j];
        }
#pragma unroll
        for (int j = 0; j < 8; ++j) {
          float bh = sl[j].x, wh = sl[j].y;
          int id = __float_as_int(sl[j].z);
          atomicAdd(&RAW[id * 129 + lane], bh * a0[j]);
          atomicAdd(&RAW[id * 129 + 64 + lane], bh * a1[j]);
          q0 += wh * a0[j] * a0[j];
          q1 += wh * a1[j] * a1[j];
        }
      }
      __builtin_amdgcn_sched_barrier(0);
      r0a = RAW[ro0]; r1a = RAW[ro1];
      r0b = RAW[ro0 + 1]; r1b = RAW[ro1 + 1];
    }

    // global prefetch rows t+2, t+3 (block base of t+2)
    const int t2 = (t + 2 < 512) ? (t + 2) : 510;
    const int nb = t2 & ~127;
    float pa0 = G[t2 * 512 + nb + lane], pa1 = G[t2 * 512 + nb + 64 + lane];
    float pb0 = G[(t2 + 1) * 512 + nb + lane], pb1 = G[(t2 + 1) * 512 + nb + 64 + lane];

    float2 uu = *(const float2*)&u_sh[t];   // off-chain broadcast

    // uniform early scalars (no dependence on this pair's decisions)
    float tr0 = rdlane_f(c < 64 ? ga0 : ga1, c & 63);
    float tr1 = rdlane_f(c1 < 64 ? gb0 : gb1, c1 & 63);
    float gx  = rdlane_f(c1 < 64 ? ga0 : ga1, c1 & 63);   // G[t, t+1]
    float ren0 = __builtin_amdgcn_rcpf(__builtin_amdgcn_sqrtf(tr0));
    float ren1 = __builtin_amdgcn_rcpf(__builtin_amdgcn_sqrtf(tr1));
    float qc0 = rdlane_f(c < 64 ? q0 : q1, c & 63);
    float qc1 = rdlane_f(c1 < 64 ? q0 : q1, c1 & 63);

    // ================= step t (chain A) =================
    float v0 = (lane < nact)      ? s0 * ren0 * r0a : -2.f;
    float v1 = (lane + 64 < nact) ? s1 * ren0 * r1a : -2.f;
    float M = wave_max64(fmaxf(v0, v1));
    unsigned long long e0 = __ballot(v0 == M), e1 = __ballot(v1 == M);
    int imax = e0 ? (__ffsll(e0) - 1) : (64 + __ffsll(e1) - 1);
    float nov = (nact == 0) ? 1.f : fminf(1.f, fmaxf(0.f, 1.f - M * M));
    int create = (nov > 0.7f && nact < 100) ? 1 : 0;
    int idx = create ? nact : imax;
    const int idxs = __builtin_amdgcn_readfirstlane(idx);
    const int cl = idxs & 63, hi = idxs >> 6;
    // per-lane update candidates (computed in parallel with the max tree)
    float dc0 = create ? 1.f : 0.95f * d0;
    float dc1 = create ? 1.f : 0.95f * d1;
    float cc0 = create ? tr0 : (0.9025f * cn0 + 0.095f * (d0 * r0a) + 0.0025f * tr0);
    float cc1 = create ? tr0 : (0.9025f * cn1 + 0.095f * (d1 * r1a) + 0.0025f * tr0);
    float sc0 = dc0 * __builtin_amdgcn_rcpf(__builtin_amdgcn_sqrtf(cc0));
    float sc1 = dc1 * __builtin_amdgcn_rcpf(__builtin_amdgcn_sqrtf(cc1));
    bool own0 = (lane == cl) && (hi == 0), own1 = (lane == cl) && (hi == 1);
    d0 = own0 ? dc0 : d0;  cn0 = own0 ? cc0 : cn0;  s0 = own0 ? sc0 : s0;
    d1 = own1 ? dc1 : d1;  cn1 = own1 ? cc1 : cn1;  s1 = own1 ? sc1 : s1;
    float bnew = create ? 1.f
                        : 0.05f * __builtin_amdgcn_rcpf(rdlane_f(hi ? dc1 : dc0, cl));
    int nact1 = nact + create;

    // patch col c1 for the one changed row
    float addv = bnew * gx;
    r0b = own0 ? r0b + addv : r0b;
    r1b = own1 ? r1b + addv : r1b;

    // ================= step t+1 (chain B) =================
    float w0 = (lane < nact1)      ? s0 * ren1 * r0b : -2.f;
    float w1 = (lane + 64 < nact1) ? s1 * ren1 * r1b : -2.f;
    float M1 = wave_max64(fmaxf(w0, w1));
    unsigned long long f0 = __ballot(w0 == M1), f1 = __ballot(w1 == M1);
    int imax1 = f0 ? (__ffsll(f0) - 1) : (64 + __ffsll(f1) - 1);
    float nov1 = (nact1 == 0) ? 1.f : fminf(1.f, fmaxf(0.f, 1.f - M1 * M1));
    int create1 = (nov1 > 0.7f && nact1 < 100) ? 1 : 0;
    int idx1 = create1 ? nact1 : imax1;
    const int idxs1 = __builtin_amdgcn_readfirstlane(idx1);
    const int cl1 = idxs1 & 63, hi1 = idxs1 >> 6;
    float dd0 = create1 ? 1.f : 0.95f * d0;
    float dd1 = create1 ? 1.f : 0.95f * d1;
    float ce0 = create1 ? tr1 : (0.9025f * cn0 + 0.095f * (d0 * r0b) + 0.0025f * tr1);
    float ce1 = create1 ? tr1 : (0.9025f * cn1 + 0.095f * (d1 * r1b) + 0.0025f * tr1);
    float se0 = dd0 * __builtin_amdgcn_rcpf(__builtin_amdgcn_sqrtf(ce0));
    float se1 = dd1 * __builtin_amdgcn_rcpf(__builtin_amdgcn_sqrtf(ce1));
    bool oo0 = (lane == cl1) && (hi1 == 0), oo1 = (lane == cl1) && (hi1 == 1);
    d0 = oo0 ? dd0 : d0;  cn0 = oo0 ? ce0 : cn0;  s0 = oo0 ? se0 : s0;
    d1 = oo1 ? dd1 : d1;  cn1 = oo1 ? ce1 : cn1;  s1 = oo1 ? se1 : s1;
    float bnew1 = create1 ? 1.f
                          : 0.05f * __builtin_amdgcn_rcpf(rdlane_f(hi1 ? dd1 : dd0, cl1));
    nact = nact1 + create1;

    // ================= DS updates + next-pair column reads =================
    atomicAdd(&RAW[idxs * 129 + lane],       bnew * ga0);
    atomicAdd(&RAW[idxs * 129 + 64 + lane],  bnew * ga1);
    atomicAdd(&RAW[idxs1 * 129 + lane],      bnew1 * gb0);
    atomicAdd(&RAW[idxs1 * 129 + 64 + lane], bnew1 * gb1);
    __builtin_amdgcn_sched_barrier(0);
    const int cnx = (t + 2) & 127;
    if (cnx) {
      r0a = RAW[ro0 + cnx];     r1a = RAW[ro1 + cnx];
      r0b = RAW[ro0 + cnx + 1]; r1b = RAW[ro1 + cnx + 1];
    }

    // ================= lag chain (off decision path) =================
    float iw = nov * __builtin_amdgcn_sqrtf(nov);
    float psc = 384.0f * __builtin_amdgcn_rcpf(fmaxf(tr0, 1e-8f));
    float ccf = A_BOOSTF * iw * psc;
    float qv = g * (uu.x + qc0);
    float n2n = n2 + 2.f * ccf * qv + ccf * ccf * tr0 * tr0;
    float kn = __builtin_amdgcn_sqrtf(n2n);
    float fct = (kn > 50.f) ? 50.f * __builtin_amdgcn_rcpf(kn) : 1.f;
    float fiv = (kn > 50.f) ? kn * 0.02f : 1.f;
    float wh = ccf * ginv;
    n2 = n2n * fct * fct; g *= fct; ginv *= fiv;

    float iw1 = nov1 * __builtin_amdgcn_sqrtf(nov1);
    float psc1 = 384.0f * __builtin_amdgcn_rcpf(fmaxf(tr1, 1e-8f));
    float ccf1 = A_BOOSTF * iw1 * psc1;
    float qv1 = g * (uu.y + qc1 + wh * gx * gx);
    float n2n1 = n2 + 2.f * ccf1 * qv1 + ccf1 * ccf1 * tr1 * tr1;
    float kn1 = __builtin_amdgcn_sqrtf(n2n1);
    float fct1 = (kn1 > 50.f) ? 50.f * __builtin_amdgcn_rcpf(kn1) : 1.f;
    float fiv1 = (kn1 > 50.f) ? kn1 * 0.02f : 1.f;
    float wh1 = ccf1 * ginv;
    n2 = n2n1 * fct1 * fct1; g *= fct1; ginv *= fiv1;

    q0 += wh * ga0 * ga0 + wh1 * gb0 * gb0;
    q1 += wh * ga1 * ga1 + wh1 * gb1 * gb1;

    if (lane == 0) {
      float4 rec0 = {bnew, wh, __int_as_float(idxs), 0.f};
      float4 rec1 = {bnew1, wh1, __int_as_float(idxs1), 0.f};
      SLOT[t] = rec0;
      SLOT[t + 1] = rec1;
    }
    ga0 = pa0; ga1 = pa1; gb0 = pb0; gb1 = pb1;
  }

  for (int s2 = lane; s2 < 512; s2 += 64) Wout[s2] = SLOT[s2].y * g;
  if (lane == 0) gOut[0] = g;
}

extern "C" void kernel_launch(void* const* d_in, const int* in_sizes, int n_in,
                              void* d_out, int out_size, void* d_ws,
                              size_t ws_size, hipStream_t stream) {
  const float* E = (const float*)d_in[0];   // [512,384]
  const float* K0 = (const float*)d_in[1];  // [384,384]
  float* out = (float*)d_out;               // [512,384]

  float* G = (float*)d_ws;                  // 512*512
  float* M0 = G + 512 * 512;                // 512*384
  float* u = M0 + 512 * 384;                // 512
  float* W = u + 512;                       // 512
  float* gS = W + 512;                      // 1
  float* Kpart = gS + 1;                    // 64

  gemm_nt<<<dim3(16, 16), 256, 0, stream>>>(E, E, G, 512, 384);     // G = E E^T
  gemm_nn<<<dim3(12, 16), 256, 0, stream>>>(E, K0, M0, 384, 384);   // M0 = E K0
  prep_kernel<<<192, 256, 0, stream>>>(E, M0, K0, u, Kpart);
  scan_kernel<<<1, 64, 0, stream>>>(G, u, Kpart, W, gS);
  final_gemm<<<dim3(12, 16), 256, 0, stream>>>(G, E, M0, W, gS, out);
}